// Round 11
// baseline (244.566 us; speedup 1.0000x reference)
//
#include <hip/hip_runtime.h>
#include <stdint.h>

typedef unsigned short u16;
typedef short bf16x8 __attribute__((ext_vector_type(8)));
typedef short bf16x4 __attribute__((ext_vector_type(4)));
typedef float f32x4 __attribute__((ext_vector_type(4)));

#define MB (1u<<20)
#define CL2 0.18033688f   // log2(e)/sqrt(DK)

static __device__ __forceinline__ u16 f2bf(float x){
  union { float f; unsigned u; } v; v.f = x;
  return (u16)((v.u + 0x7FFFu + ((v.u >> 16) & 1u)) >> 16);
}

static __device__ __forceinline__ void gld_lds16(const void* g, void* l){
  __builtin_amdgcn_global_load_lds((const __attribute__((address_space(1))) unsigned int*)g,
                                   (__attribute__((address_space(3))) unsigned int*)l, 16, 0, 0);
}

// round-half-up f32 pair -> packed bf16x2 via v_perm (r4-verified; do NOT use
// v_cvt_pk_bf16_f32 here — r5 showed it breaks numerics on this toolchain).
static __device__ __forceinline__ int pack_bf16(float a, float b){
  unsigned ua = __float_as_uint(a) + 0x8000u;
  unsigned ub = __float_as_uint(b) + 0x8000u;
  return (int)__builtin_amdgcn_perm(ub, ua, 0x07060302u);
}

// ------------- weight transpose + convert: Wt[n][k] = bf16(W[k][n]) -------------
// r11: qkv activations are converted inside qkv_gemm now (fused); only weights here.
__global__ void convw(const float* W0,const float* W1,const float* W2,const float* W3,const float* W4,
                      u16* T0,u16* T1,u16* T2,u16* T3,u16* T4){
  const float* W = blockIdx.z==0?W0:blockIdx.z==1?W1:blockIdx.z==2?W2:blockIdx.z==3?W3:W4;
  u16* T = blockIdx.z==0?T0:blockIdx.z==1?T1:blockIdx.z==2?T2:blockIdx.z==3?T3:T4;
  __shared__ u16 t[64][65];
  int k0 = blockIdx.x*64, n0 = blockIdx.y*64;
  for (int i=0;i<16;i++){
    int idx = i*256 + threadIdx.x;
    int r = idx >> 6, c = idx & 63;
    t[r][c] = f2bf(W[(size_t)(k0+r)*1024 + n0 + c]);
  }
  __syncthreads();
  for (int i=0;i<2;i++){
    int idx = i*256 + threadIdx.x;
    int nl = idx >> 3, kc = idx & 7;
    bf16x8 o;
    #pragma unroll
    for (int j=0;j<8;j++) o[j] = (short)t[kc*8+j][nl];
    *(bf16x8*)(T + (size_t)(n0+nl)*1024 + k0 + kc*8) = o;
  }
}

// ---------------- 128x128 bf16 MFMA GEMM, B pre-transposed (Bt[n][k]) ----------------
// BK=64; LDS at kernel scope passed in (r3 lesson). 3-bit XOR swizzle keeps
// ds_read_b128 conflict-free. XCD-aware bijective block swizzle for L2 locality.
// AF32=true: A is f32 in global; staged via global->reg->f2bf->ds_write (fuses the
// old convx kernel; T14 split — next K-step's loads issue right after the barrier
// and hide under the MFMA phase). The LDS slot layout (slot sg holds k-group
// sg^(row&7)) is IDENTICAL to the gld_lds16 path, so the read side is unchanged.
// MODE 0: bf16 row-major; 1: f32 row-major; 2: K attn layout; 3: V attn layout
// (x32-PV fragment order, see attn); 4: bf16 *CL2 (Q)
template<int MODE, bool AF32>
static __device__ __forceinline__ void gemm_bt_dev(u16* __restrict__ As, u16* __restrict__ Bs,
                                                   const void* __restrict__ Av, const u16* __restrict__ Bt,
                                                   const float* __restrict__ bias, void* __restrict__ Cout){
  const int tid = threadIdx.x, lane = tid & 63, w = tid >> 6;
  const int wm = w >> 1, wn = w & 1, quad = lane >> 4, lr = lane & 15;
  // bijective XCD swizzle over the 256 blocks of this z-slice (grid 8 x 32, nwg%8==0)
  const int fid = blockIdx.y * 8 + blockIdx.x;
  const int o   = (fid & 7) * 32 + (fid >> 3);
  const int n0  = (o & 7) * 128, m0 = (o >> 3) * 128;
  f32x4 acc[4][4] = {};
  const float* Af = (const float*)Av + (size_t)m0*1024;
  const u16*   Ab = (const u16*)Av + (size_t)m0*1024;
  const u16*   Bb = Bt + (size_t)n0*1024;
  // staging: 8 lanes per 128B row; issue j covers rows j*32 + w*8 .. +8
  const int srow_base = w*8 + (lane >> 3);
  const int sg = lane & 7;

  bf16x8 areg[4];
  auto LOADA = [&](int kn){
    #pragma unroll
    for (int j=0;j<4;++j){
      int row = j*32 + srow_base;
      int g = sg ^ (row & 7);
      const float* ap = Af + (size_t)row*1024 + kn + g*8;
      float4 f0 = *(const float4*)ap;
      float4 f1 = *(const float4*)(ap+4);
      bf16x8 r;
      r[0]=(short)f2bf(f0.x); r[1]=(short)f2bf(f0.y); r[2]=(short)f2bf(f0.z); r[3]=(short)f2bf(f0.w);
      r[4]=(short)f2bf(f1.x); r[5]=(short)f2bf(f1.y); r[6]=(short)f2bf(f1.z); r[7]=(short)f2bf(f1.w);
      areg[j] = r;
    }
  };
  if constexpr (AF32) LOADA(0);

  for (int k0 = 0; k0 < 1024; k0 += 64){
    if constexpr (AF32){
      #pragma unroll
      for (int j = 0; j < 4; ++j){
        int row = j*32 + srow_base;
        *(bf16x8*)(As + row*64 + sg*8) = areg[j];       // slot sg holds group sg^(row&7)
        int g = sg ^ (row & 7);
        gld_lds16(Bb + (size_t)row*1024 + k0 + g*8, Bs + (j*32 + w*8)*64);
      }
      __syncthreads();
      if (k0 < 960) LOADA(k0 + 64);                     // overlap with MFMA phase below
    } else {
      #pragma unroll
      for (int j = 0; j < 4; ++j){
        int row = j*32 + srow_base;
        int g = sg ^ (row & 7);
        gld_lds16(Ab + (size_t)row*1024 + k0 + g*8, As + (j*32 + w*8)*64);
        gld_lds16(Bb + (size_t)row*1024 + k0 + g*8, Bs + (j*32 + w*8)*64);
      }
      __syncthreads();
    }
    #pragma unroll
    for (int kk = 0; kk < 2; ++kk){
      bf16x8 af[4], bfr[4];
      #pragma unroll
      for (int i=0;i<4;i++){
        int ra = wm*64 + i*16 + lr;
        af[i]  = *(const bf16x8*)(As + ra*64 + (((kk*4+quad) ^ (ra & 7)))*8);
        int rb = wn*64 + i*16 + lr;
        bfr[i] = *(const bf16x8*)(Bs + rb*64 + (((kk*4+quad) ^ (rb & 7)))*8);
      }
      #pragma unroll
      for (int mi=0;mi<4;mi++)
        #pragma unroll
        for (int ni=0;ni<4;ni++)
          acc[mi][ni] = __builtin_amdgcn_mfma_f32_16x16x32_bf16(af[mi], bfr[ni], acc[mi][ni], 0, 0, 0);
    }
    __syncthreads();
  }
  #pragma unroll
  for (int mi=0;mi<4;mi++){
    int row = m0 + wm*64 + mi*16 + quad*4;
    #pragma unroll
    for (int ni=0;ni<4;ni++){
      int col = n0 + wn*64 + ni*16 + lr;
      float bb = bias[col];
      #pragma unroll
      for (int rg=0; rg<4; rg++){
        float vv = acc[mi][ni][rg] + bb;
        int r = row + rg;
        if (MODE == 0){
          ((u16*)Cout)[(size_t)r*1024 + col] = f2bf(vv);
        } else if (MODE == 4){
          ((u16*)Cout)[(size_t)r*1024 + col] = f2bf(vv * CL2);
        } else if (MODE == 1){
          ((float*)Cout)[(size_t)r*1024 + col] = vv;
        } else if (MODE == 2){
          // K: [bh][kb=16][hg=8][kvl=128][hl=8]
          int b2 = r >> 11, s = r & 2047, kb2 = s >> 7, kvl = s & 127;
          int hh = col >> 6, hg = (col & 63) >> 3, hl = col & 7;
          ((u16*)Cout)[((size_t)(b2*16+hh)*16 + kb2)*8192 + hg*1024 + kvl*8 + hl] = f2bf(vv);
        } else {
          // V for x32 PV: [bh][kb=16][mt2g=16][dd=64][j=8]
          // kv = 32*mt2 + 16*(j>>2) + 4*g + (j&3); elem = (mt2*4+g)*512 + dd*8 + j
          int b2 = r >> 11, s = r & 2047, kb2 = s >> 7, kvl = s & 127;
          int mt2v = kvl >> 5, gv = (kvl >> 2) & 3, jv = ((kvl >> 4) & 1)*4 + (kvl & 3);
          int hh = col >> 6, dd = col & 63;
          ((u16*)Cout)[((size_t)(b2*16+hh)*16 + kb2)*8192 + (size_t)(mt2v*4+gv)*512 + dd*8 + jv] = f2bf(vv);
        }
      }
    }
  }
}

__global__ void qkv_gemm(const float* q,const float* k,const float* v,
                         const u16* Wqt,const u16* Wkt,const u16* Wvt,
                         const float* bq,const float* bk,const float* bv,
                         u16* Qb,u16* Kr,u16* Vr){
  __shared__ u16 As[128*64];
  __shared__ u16 Bs[128*64];
  if (blockIdx.z == 0)      gemm_bt_dev<4,true>(As, Bs, q, Wqt, bq, Qb);   // Q pre-scaled by CL2
  else if (blockIdx.z == 1) gemm_bt_dev<2,true>(As, Bs, k, Wkt, bk, Kr);
  else                      gemm_bt_dev<3,true>(As, Bs, v, Wvt, bv, Vr);
}

__global__ void out_gemm(const u16* Mg, const u16* Wct, const u16* Wot,
                         const float* bc, const float* bo, float* out){
  __shared__ u16 As[128*64];
  __shared__ u16 Bs[128*64];
  const u16* B = blockIdx.z==0? Wct : Wot;
  const float* bias = blockIdx.z==0? bc : bo;
  float* C = out + (blockIdx.z==0? 0 : 4194304);   // (c, h) concatenated
  gemm_bt_dev<1,false>(As, Bs, Mg, B, bias, C);
}

// ---------------- flash attention, transposed-score, no-max softmax ----------------
// r11 = r7/r9 geometry (best measured: 45.8 us) + T5 s_setprio around MFMA clusters
// (2 independent blocks/CU at different phases -> scheduler has something to
// arbitrate; m191 mechanism). r8/r10 proved occupancy and per-block amortization
// are NOT the levers; structure otherwise frozen.
// block = 256 threads (4 waves); each wave owns 32 q; KV-block = 128; dbuf LDS 64KB;
// PV/l on native 16x16x32 via pre-permuted V (MODE-3 epilogue), zero shuffles.
__global__ __launch_bounds__(256,2) void attn(const u16* __restrict__ Qb, const u16* __restrict__ Kr,
                                              const u16* __restrict__ Vr, u16* __restrict__ Mg){
  __shared__ u16 Ks[2][8192];
  __shared__ u16 Vs[2][8192];
  const int fid = blockIdx.y * 16 + blockIdx.x;        // nwg = 512, %8 == 0
  const int o   = (fid & 7) * 64 + (fid >> 3);
  const int qt = o & 15, bh = o >> 4, b = bh >> 4, h = bh & 15;
  const int tid = threadIdx.x, lane = tid & 63, w = tid >> 6;
  const int quad = lane >> 4, lr = lane & 15;
  const int q0 = qt*128 + w*32;

  bf16x8 aq[2][2];   // [q-subtile][ks]; Q pre-scaled by CL2
  #pragma unroll
  for (int t=0;t<2;t++)
    #pragma unroll
    for (int ks=0;ks<2;ks++)
      aq[t][ks] = *(const bf16x8*)(Qb + (size_t)(b*2048 + q0 + t*16 + lr)*1024 + h*64 + ks*32 + quad*8);

  f32x4 acco[2][4] = {};
  f32x4 accl[2] = {};
  const bf16x8 ones8 = {(short)0x3F80,(short)0x3F80,(short)0x3F80,(short)0x3F80,
                        (short)0x3F80,(short)0x3F80,(short)0x3F80,(short)0x3F80};

  const u16* Krb = Kr + (size_t)bh*131072;   // 16 kv-blocks * 8192 elems
  const u16* Vrb = Vr + (size_t)bh*131072;

  // prefetch kv-block 0 (4 chunks of 4 KB each per buffer)
  #pragma unroll
  for (int j=0;j<4;j++){
    gld_lds16(Krb + j*2048 + tid*8, &Ks[0][j*2048 + w*512]);
    gld_lds16(Vrb + j*2048 + tid*8, &Vs[0][j*2048 + w*512]);
  }

  for (int kb = 0; kb < 16; kb++){
    __syncthreads();                       // staged data for kb now visible
    const int cur = kb & 1;
    if (kb < 15){
      const u16* kg = Krb + (size_t)(kb+1)*8192;
      const u16* vg = Vrb + (size_t)(kb+1)*8192;
      #pragma unroll
      for (int j=0;j<4;j++){
        gld_lds16(kg + j*2048 + tid*8, &Ks[cur^1][j*2048 + w*512]);
        gld_lds16(vg + j*2048 + tid*8, &Vs[cur^1][j*2048 + w*512]);
      }
    }
    const u16* Ksc = Ks[cur];
    const u16* Vsc = Vs[cur];

    // ---- per 32-kv pair of subtiles: QK -> exp/pack -> l -> PV, all native x32 ----
    #pragma unroll
    for (int mt2=0;mt2<4;mt2++){
      f32x4 ae0 = {}, ae1 = {}, ao0 = {}, ao1 = {};
      __builtin_amdgcn_s_setprio(1);
      {
        bf16x8 kf0 = *(const bf16x8*)(Ksc + (0*4+quad)*1024 + ((2*mt2)*16+lr)*8);
        bf16x8 kf1 = *(const bf16x8*)(Ksc + (1*4+quad)*1024 + ((2*mt2)*16+lr)*8);
        ae0 = __builtin_amdgcn_mfma_f32_16x16x32_bf16(kf0, aq[0][0], ae0, 0,0,0);
        ae1 = __builtin_amdgcn_mfma_f32_16x16x32_bf16(kf0, aq[1][0], ae1, 0,0,0);
        ae0 = __builtin_amdgcn_mfma_f32_16x16x32_bf16(kf1, aq[0][1], ae0, 0,0,0);
        ae1 = __builtin_amdgcn_mfma_f32_16x16x32_bf16(kf1, aq[1][1], ae1, 0,0,0);
      }
      {
        bf16x8 kf0 = *(const bf16x8*)(Ksc + (0*4+quad)*1024 + ((2*mt2+1)*16+lr)*8);
        bf16x8 kf1 = *(const bf16x8*)(Ksc + (1*4+quad)*1024 + ((2*mt2+1)*16+lr)*8);
        ao0 = __builtin_amdgcn_mfma_f32_16x16x32_bf16(kf0, aq[0][0], ao0, 0,0,0);
        ao1 = __builtin_amdgcn_mfma_f32_16x16x32_bf16(kf0, aq[1][0], ao1, 0,0,0);
        ao0 = __builtin_amdgcn_mfma_f32_16x16x32_bf16(kf1, aq[0][1], ao0, 0,0,0);
        ao1 = __builtin_amdgcn_mfma_f32_16x16x32_bf16(kf1, aq[1][1], ao1, 0,0,0);
      }
      __builtin_amdgcn_s_setprio(0);

      // p = exp2(s'); pack even-mt into elems 0..3, odd-mt into 4..7 (x32 B-frag order)
      union { int4 i4; bf16x8 v; } pf0, pf1;
      pf0.i4.x = pack_bf16(__builtin_amdgcn_exp2f(ae0[0]), __builtin_amdgcn_exp2f(ae0[1]));
      pf0.i4.y = pack_bf16(__builtin_amdgcn_exp2f(ae0[2]), __builtin_amdgcn_exp2f(ae0[3]));
      pf0.i4.z = pack_bf16(__builtin_amdgcn_exp2f(ao0[0]), __builtin_amdgcn_exp2f(ao0[1]));
      pf0.i4.w = pack_bf16(__builtin_amdgcn_exp2f(ao0[2]), __builtin_amdgcn_exp2f(ao0[3]));
      pf1.i4.x = pack_bf16(__builtin_amdgcn_exp2f(ae1[0]), __builtin_amdgcn_exp2f(ae1[1]));
      pf1.i4.y = pack_bf16(__builtin_amdgcn_exp2f(ae1[2]), __builtin_amdgcn_exp2f(ae1[3]));
      pf1.i4.z = pack_bf16(__builtin_amdgcn_exp2f(ao1[0]), __builtin_amdgcn_exp2f(ao1[1]));
      pf1.i4.w = pack_bf16(__builtin_amdgcn_exp2f(ao1[2]), __builtin_amdgcn_exp2f(ao1[3]));

      __builtin_amdgcn_s_setprio(1);
      // l via native x32: every C row = sum over this 32-kv chunk
      accl[0] = __builtin_amdgcn_mfma_f32_16x16x32_bf16(ones8, pf0.v, accl[0], 0,0,0);
      accl[1] = __builtin_amdgcn_mfma_f32_16x16x32_bf16(ones8, pf1.v, accl[1], 0,0,0);

      // O^T += V^T * P^T (32 kv per op; vf read feeds both q-subtiles)
      #pragma unroll
      for (int dt=0;dt<4;dt++){
        bf16x8 vf = *(const bf16x8*)(Vsc + (mt2*4+quad)*512 + (dt*16+lr)*8);
        acco[0][dt] = __builtin_amdgcn_mfma_f32_16x16x32_bf16(vf, pf0.v, acco[0][dt], 0,0,0);
        acco[1][dt] = __builtin_amdgcn_mfma_f32_16x16x32_bf16(vf, pf1.v, acco[1][dt], 0,0,0);
      }
      __builtin_amdgcn_s_setprio(0);
    }
  }

  // ---- epilogue: accl rows are all identical = l(q=lane&15); lane-local ----
  #pragma unroll
  for (int t=0;t<2;t++){
    float inv = 1.f / accl[t][0];
    u16* dst = Mg + (size_t)(b*2048 + q0 + t*16 + lr)*1024 + h*64;
    #pragma unroll
    for (int dt=0;dt<4;dt++){
      bf16x4 o2;
      #pragma unroll
      for (int rg=0;rg<4;rg++) o2[rg] = (short)f2bf(acco[t][dt][rg]*inv);
      *(bf16x4*)(dst + dt*16 + quad*4) = o2;
    }
  }
}

extern "C" void kernel_launch(void* const* d_in, const int* in_sizes, int n_in,
                              void* d_out, int out_size, void* d_ws, size_t ws_size,
                              hipStream_t stream){
  const float* q  = (const float*)d_in[0];
  const float* k  = (const float*)d_in[1];
  const float* v  = (const float*)d_in[2];
  const float* Wq = (const float*)d_in[3];
  const float* bq = (const float*)d_in[4];
  const float* Wk = (const float*)d_in[5];
  const float* bk = (const float*)d_in[6];
  const float* Wv = (const float*)d_in[7];
  const float* bv = (const float*)d_in[8];
  const float* Wo = (const float*)d_in[9];
  const float* bo = (const float*)d_in[10];
  const float* Wc = (const float*)d_in[11];
  const float* bc = (const float*)d_in[12];
  char* ws = (char*)d_ws;
  u16* Wqt = (u16*)(ws + (size_t)24*MB);
  u16* Wkt = (u16*)(ws + (size_t)26*MB);
  u16* Wvt = (u16*)(ws + (size_t)28*MB);
  u16* Wot = (u16*)(ws + (size_t)30*MB);
  u16* Wct = (u16*)(ws + (size_t)32*MB);
  u16* Qb  = (u16*)(ws + (size_t)34*MB);
  u16* Kr  = (u16*)(ws + (size_t)42*MB);
  u16* Vr  = (u16*)(ws + (size_t)50*MB);
  u16* Mg  = (u16*)(ws + (size_t)58*MB);

  dim3 blk(256,1,1);
  hipLaunchKernelGGL(convw,    dim3(16,16,5),  blk, 0, stream, Wq,Wk,Wv,Wo,Wc, Wqt,Wkt,Wvt,Wot,Wct);
  hipLaunchKernelGGL(qkv_gemm, dim3(8,32,3),   blk, 0, stream, q,k,v, Wqt,Wkt,Wvt, bq,bk,bv, Qb,Kr,Vr);
  hipLaunchKernelGGL(attn,     dim3(16,32,1),  blk, 0, stream, Qb, Kr, Vr, Mg);
  hipLaunchKernelGGL(out_gemm, dim3(8,32,2),   blk, 0, stream, Mg, Wct, Wot, bc, bo, (float*)d_out);
}

// Round 12
// 228.865 us; speedup vs baseline: 1.0686x; 1.0686x over previous
//
#include <hip/hip_runtime.h>
#include <stdint.h>

typedef unsigned short u16;
typedef short bf16x8 __attribute__((ext_vector_type(8)));
typedef short bf16x4 __attribute__((ext_vector_type(4)));
typedef float f32x4 __attribute__((ext_vector_type(4)));

#define MB (1u<<20)
#define CL2 0.18033688f   // log2(e)/sqrt(DK)

static __device__ __forceinline__ u16 f2bf(float x){
  union { float f; unsigned u; } v; v.f = x;
  return (u16)((v.u + 0x7FFFu + ((v.u >> 16) & 1u)) >> 16);
}

static __device__ __forceinline__ void gld_lds16(const void* g, void* l){
  __builtin_amdgcn_global_load_lds((const __attribute__((address_space(1))) unsigned int*)g,
                                   (__attribute__((address_space(3))) unsigned int*)l, 16, 0, 0);
}

// round-half-up f32 pair -> packed bf16x2 via v_perm (r4-verified; do NOT use
// v_cvt_pk_bf16_f32 here — r5 showed it breaks numerics on this toolchain).
static __device__ __forceinline__ int pack_bf16(float a, float b){
  unsigned ua = __float_as_uint(a) + 0x8000u;
  unsigned ub = __float_as_uint(b) + 0x8000u;
  return (int)__builtin_amdgcn_perm(ub, ua, 0x07060302u);
}

// ------------- fused prologue: qkv f32->bf16 (z<3) + weight transpose (z==3) -------------
// r12: back to the r9 structure. r11's in-GEMM A-conversion REGRESSED (f32 A = 2x
// operand bytes x 32-panel reuse >> the 24 MB conv round-trip; reg-staging also
// lost async global_load_lds). bf16-ize once here, stream bf16 in the GEMM.
__global__ void conv_all(const float* __restrict__ q, const float* __restrict__ k, const float* __restrict__ v,
                         u16* __restrict__ qb, u16* __restrict__ kb, u16* __restrict__ vb,
                         const float* W0,const float* W1,const float* W2,const float* W3,const float* W4,
                         u16* T0,u16* T1,u16* T2,u16* T3,u16* T4){
  __shared__ u16 t[64][65];
  if (blockIdx.z < 3){
    const float* s = blockIdx.z==0 ? q : (blockIdx.z==1 ? k : v);
    u16* d = blockIdx.z==0 ? qb : (blockIdx.z==1 ? kb : vb);
    int i = (blockIdx.x*256 + threadIdx.x)*4;
    float4 f = *(const float4*)(s + i);
    ushort4 o; o.x=f2bf(f.x); o.y=f2bf(f.y); o.z=f2bf(f.z); o.w=f2bf(f.w);
    *(ushort4*)(d + i) = o;
    return;
  }
  if (blockIdx.x >= 1280) return;          // 5 weights x 256 tiles
  const int wsel = blockIdx.x >> 8;
  const float* W = wsel==0?W0:wsel==1?W1:wsel==2?W2:wsel==3?W3:W4;
  u16* T = wsel==0?T0:wsel==1?T1:wsel==2?T2:wsel==3?T3:T4;
  const int idx2 = blockIdx.x & 255;
  int k0 = (idx2 & 15)*64, n0 = (idx2 >> 4)*64;
  for (int i=0;i<16;i++){
    int idx = i*256 + threadIdx.x;
    int r = idx >> 6, c = idx & 63;
    t[r][c] = f2bf(W[(size_t)(k0+r)*1024 + n0 + c]);
  }
  __syncthreads();
  for (int i=0;i<2;i++){
    int idx = i*256 + threadIdx.x;
    int nl = idx >> 3, kc = idx & 7;
    bf16x8 o;
    #pragma unroll
    for (int j=0;j<8;j++) o[j] = (short)t[kc*8+j][nl];
    *(bf16x8*)(T + (size_t)(n0+nl)*1024 + k0 + kc*8) = o;
  }
}

// ---------------- 128x128 bf16 MFMA GEMM, B pre-transposed (Bt[n][k]) ----------------
// BK=64; LDS declared once at kernel scope and passed in (r3: per-instantiation
// __shared__ tripled LDS -> 1 block/CU). 3-bit XOR swizzle keeps ds_read_b128
// conflict-free. XCD-aware bijective block swizzle for L2 locality.
// MODE 0: bf16 row-major; 1: f32 row-major; 2: K attn layout; 3: V attn layout
// (x32-PV fragment order, see attn); 4: bf16 *CL2 (Q)
template<int MODE>
static __device__ __forceinline__ void gemm_bt_dev(u16* __restrict__ As, u16* __restrict__ Bs,
                                                   const u16* __restrict__ A, const u16* __restrict__ Bt,
                                                   const float* __restrict__ bias, void* __restrict__ Cout){
  const int tid = threadIdx.x, lane = tid & 63, w = tid >> 6;
  const int wm = w >> 1, wn = w & 1, quad = lane >> 4, lr = lane & 15;
  // bijective XCD swizzle over the 256 blocks of this z-slice (grid 8 x 32, nwg%8==0)
  const int fid = blockIdx.y * 8 + blockIdx.x;
  const int o   = (fid & 7) * 32 + (fid >> 3);
  const int n0  = (o & 7) * 128, m0 = (o >> 3) * 128;
  f32x4 acc[4][4] = {};
  const u16* Ab = A + (size_t)m0*1024;
  const u16* Bb = Bt + (size_t)n0*1024;
  // staging: 8 lanes per 128B row; issue j covers rows j*32 + w*8 .. +8
  const int srow_base = w*8 + (lane >> 3);
  const int sg = lane & 7;
  for (int k0 = 0; k0 < 1024; k0 += 64){
    #pragma unroll
    for (int j = 0; j < 4; ++j){
      int row = j*32 + srow_base;
      int g = sg ^ (row & 7);
      gld_lds16(Ab + (size_t)row*1024 + k0 + g*8, As + (j*32 + w*8)*64);
      gld_lds16(Bb + (size_t)row*1024 + k0 + g*8, Bs + (j*32 + w*8)*64);
    }
    __syncthreads();
    #pragma unroll
    for (int kk = 0; kk < 2; ++kk){
      bf16x8 af[4], bfr[4];
      #pragma unroll
      for (int i=0;i<4;i++){
        int ra = wm*64 + i*16 + lr;
        af[i]  = *(const bf16x8*)(As + ra*64 + (((kk*4+quad) ^ (ra & 7)))*8);
        int rb = wn*64 + i*16 + lr;
        bfr[i] = *(const bf16x8*)(Bs + rb*64 + (((kk*4+quad) ^ (rb & 7)))*8);
      }
      #pragma unroll
      for (int mi=0;mi<4;mi++)
        #pragma unroll
        for (int ni=0;ni<4;ni++)
          acc[mi][ni] = __builtin_amdgcn_mfma_f32_16x16x32_bf16(af[mi], bfr[ni], acc[mi][ni], 0, 0, 0);
    }
    __syncthreads();
  }
  #pragma unroll
  for (int mi=0;mi<4;mi++){
    int row = m0 + wm*64 + mi*16 + quad*4;
    #pragma unroll
    for (int ni=0;ni<4;ni++){
      int col = n0 + wn*64 + ni*16 + lr;
      float bb = bias[col];
      #pragma unroll
      for (int rg=0; rg<4; rg++){
        float vv = acc[mi][ni][rg] + bb;
        int r = row + rg;
        if (MODE == 0){
          ((u16*)Cout)[(size_t)r*1024 + col] = f2bf(vv);
        } else if (MODE == 4){
          ((u16*)Cout)[(size_t)r*1024 + col] = f2bf(vv * CL2);
        } else if (MODE == 1){
          ((float*)Cout)[(size_t)r*1024 + col] = vv;
        } else if (MODE == 2){
          // K: [bh][kb=16][hg=8][kvl=128][hl=8]
          int b2 = r >> 11, s = r & 2047, kb2 = s >> 7, kvl = s & 127;
          int hh = col >> 6, hg = (col & 63) >> 3, hl = col & 7;
          ((u16*)Cout)[((size_t)(b2*16+hh)*16 + kb2)*8192 + hg*1024 + kvl*8 + hl] = f2bf(vv);
        } else {
          // V for x32 PV: [bh][kb=16][mt2g=16][dd=64][j=8]
          // kv = 32*mt2 + 16*(j>>2) + 4*g + (j&3); elem = (mt2*4+g)*512 + dd*8 + j
          int b2 = r >> 11, s = r & 2047, kb2 = s >> 7, kvl = s & 127;
          int mt2v = kvl >> 5, gv = (kvl >> 2) & 3, jv = ((kvl >> 4) & 1)*4 + (kvl & 3);
          int hh = col >> 6, dd = col & 63;
          ((u16*)Cout)[((size_t)(b2*16+hh)*16 + kb2)*8192 + (size_t)(mt2v*4+gv)*512 + dd*8 + jv] = f2bf(vv);
        }
      }
    }
  }
}

__global__ void qkv_gemm(const u16* qb,const u16* kb,const u16* vb,
                         const u16* Wqt,const u16* Wkt,const u16* Wvt,
                         const float* bq,const float* bk,const float* bv,
                         u16* Qb,u16* Kr,u16* Vr){
  __shared__ u16 As[128*64];
  __shared__ u16 Bs[128*64];
  if (blockIdx.z == 0)      gemm_bt_dev<4>(As, Bs, qb, Wqt, bq, Qb);   // Q pre-scaled by CL2
  else if (blockIdx.z == 1) gemm_bt_dev<2>(As, Bs, kb, Wkt, bk, Kr);
  else                      gemm_bt_dev<3>(As, Bs, vb, Wvt, bv, Vr);
}

__global__ void out_gemm(const u16* Mg, const u16* Wct, const u16* Wot,
                         const float* bc, const float* bo, float* out){
  __shared__ u16 As[128*64];
  __shared__ u16 Bs[128*64];
  const u16* B = blockIdx.z==0? Wct : Wot;
  const float* bias = blockIdx.z==0? bc : bo;
  float* C = out + (blockIdx.z==0? 0 : 4194304);   // (c, h) concatenated
  gemm_bt_dev<1>(As, Bs, Mg, B, bias, C);
}

// ---------------- flash attention, transposed-score, no-max softmax ----------------
// r12 = r7/r9 geometry (best measured attn: 45.8-46.2 us) + T5 s_setprio around the
// MFMA clusters (2 independent blocks/CU at different phases; m191 mechanism).
// This round cleanly A/Bs setprio vs r9's attn=46.2 (r11's qkv regression masked it).
// r8/r10 proved occupancy and per-block amortization are NOT the levers.
__global__ __launch_bounds__(256,2) void attn(const u16* __restrict__ Qb, const u16* __restrict__ Kr,
                                              const u16* __restrict__ Vr, u16* __restrict__ Mg){
  __shared__ u16 Ks[2][8192];
  __shared__ u16 Vs[2][8192];
  const int fid = blockIdx.y * 16 + blockIdx.x;        // nwg = 512, %8 == 0
  const int o   = (fid & 7) * 64 + (fid >> 3);
  const int qt = o & 15, bh = o >> 4, b = bh >> 4, h = bh & 15;
  const int tid = threadIdx.x, lane = tid & 63, w = tid >> 6;
  const int quad = lane >> 4, lr = lane & 15;
  const int q0 = qt*128 + w*32;

  bf16x8 aq[2][2];   // [q-subtile][ks]; Q pre-scaled by CL2
  #pragma unroll
  for (int t=0;t<2;t++)
    #pragma unroll
    for (int ks=0;ks<2;ks++)
      aq[t][ks] = *(const bf16x8*)(Qb + (size_t)(b*2048 + q0 + t*16 + lr)*1024 + h*64 + ks*32 + quad*8);

  f32x4 acco[2][4] = {};
  f32x4 accl[2] = {};
  const bf16x8 ones8 = {(short)0x3F80,(short)0x3F80,(short)0x3F80,(short)0x3F80,
                        (short)0x3F80,(short)0x3F80,(short)0x3F80,(short)0x3F80};

  const u16* Krb = Kr + (size_t)bh*131072;   // 16 kv-blocks * 8192 elems
  const u16* Vrb = Vr + (size_t)bh*131072;

  // prefetch kv-block 0 (4 chunks of 4 KB each per buffer)
  #pragma unroll
  for (int j=0;j<4;j++){
    gld_lds16(Krb + j*2048 + tid*8, &Ks[0][j*2048 + w*512]);
    gld_lds16(Vrb + j*2048 + tid*8, &Vs[0][j*2048 + w*512]);
  }

  for (int kb = 0; kb < 16; kb++){
    __syncthreads();                       // staged data for kb now visible
    const int cur = kb & 1;
    if (kb < 15){
      const u16* kg = Krb + (size_t)(kb+1)*8192;
      const u16* vg = Vrb + (size_t)(kb+1)*8192;
      #pragma unroll
      for (int j=0;j<4;j++){
        gld_lds16(kg + j*2048 + tid*8, &Ks[cur^1][j*2048 + w*512]);
        gld_lds16(vg + j*2048 + tid*8, &Vs[cur^1][j*2048 + w*512]);
      }
    }
    const u16* Ksc = Ks[cur];
    const u16* Vsc = Vs[cur];

    // ---- per 32-kv pair of subtiles: QK -> exp/pack -> l -> PV, all native x32 ----
    #pragma unroll
    for (int mt2=0;mt2<4;mt2++){
      f32x4 ae0 = {}, ae1 = {}, ao0 = {}, ao1 = {};
      __builtin_amdgcn_s_setprio(1);
      {
        bf16x8 kf0 = *(const bf16x8*)(Ksc + (0*4+quad)*1024 + ((2*mt2)*16+lr)*8);
        bf16x8 kf1 = *(const bf16x8*)(Ksc + (1*4+quad)*1024 + ((2*mt2)*16+lr)*8);
        ae0 = __builtin_amdgcn_mfma_f32_16x16x32_bf16(kf0, aq[0][0], ae0, 0,0,0);
        ae1 = __builtin_amdgcn_mfma_f32_16x16x32_bf16(kf0, aq[1][0], ae1, 0,0,0);
        ae0 = __builtin_amdgcn_mfma_f32_16x16x32_bf16(kf1, aq[0][1], ae0, 0,0,0);
        ae1 = __builtin_amdgcn_mfma_f32_16x16x32_bf16(kf1, aq[1][1], ae1, 0,0,0);
      }
      {
        bf16x8 kf0 = *(const bf16x8*)(Ksc + (0*4+quad)*1024 + ((2*mt2+1)*16+lr)*8);
        bf16x8 kf1 = *(const bf16x8*)(Ksc + (1*4+quad)*1024 + ((2*mt2+1)*16+lr)*8);
        ao0 = __builtin_amdgcn_mfma_f32_16x16x32_bf16(kf0, aq[0][0], ao0, 0,0,0);
        ao1 = __builtin_amdgcn_mfma_f32_16x16x32_bf16(kf0, aq[1][0], ao1, 0,0,0);
        ao0 = __builtin_amdgcn_mfma_f32_16x16x32_bf16(kf1, aq[0][1], ao0, 0,0,0);
        ao1 = __builtin_amdgcn_mfma_f32_16x16x32_bf16(kf1, aq[1][1], ao1, 0,0,0);
      }
      __builtin_amdgcn_s_setprio(0);

      // p = exp2(s'); pack even-mt into elems 0..3, odd-mt into 4..7 (x32 B-frag order)
      union { int4 i4; bf16x8 v; } pf0, pf1;
      pf0.i4.x = pack_bf16(__builtin_amdgcn_exp2f(ae0[0]), __builtin_amdgcn_exp2f(ae0[1]));
      pf0.i4.y = pack_bf16(__builtin_amdgcn_exp2f(ae0[2]), __builtin_amdgcn_exp2f(ae0[3]));
      pf0.i4.z = pack_bf16(__builtin_amdgcn_exp2f(ao0[0]), __builtin_amdgcn_exp2f(ao0[1]));
      pf0.i4.w = pack_bf16(__builtin_amdgcn_exp2f(ao0[2]), __builtin_amdgcn_exp2f(ao0[3]));
      pf1.i4.x = pack_bf16(__builtin_amdgcn_exp2f(ae1[0]), __builtin_amdgcn_exp2f(ae1[1]));
      pf1.i4.y = pack_bf16(__builtin_amdgcn_exp2f(ae1[2]), __builtin_amdgcn_exp2f(ae1[3]));
      pf1.i4.z = pack_bf16(__builtin_amdgcn_exp2f(ao1[0]), __builtin_amdgcn_exp2f(ao1[1]));
      pf1.i4.w = pack_bf16(__builtin_amdgcn_exp2f(ao1[2]), __builtin_amdgcn_exp2f(ao1[3]));

      __builtin_amdgcn_s_setprio(1);
      // l via native x32: every C row = sum over this 32-kv chunk
      accl[0] = __builtin_amdgcn_mfma_f32_16x16x32_bf16(ones8, pf0.v, accl[0], 0,0,0);
      accl[1] = __builtin_amdgcn_mfma_f32_16x16x32_bf16(ones8, pf1.v, accl[1], 0,0,0);

      // O^T += V^T * P^T (32 kv per op; vf read feeds both q-subtiles)
      #pragma unroll
      for (int dt=0;dt<4;dt++){
        bf16x8 vf = *(const bf16x8*)(Vsc + (mt2*4+quad)*512 + (dt*16+lr)*8);
        acco[0][dt] = __builtin_amdgcn_mfma_f32_16x16x32_bf16(vf, pf0.v, acco[0][dt], 0,0,0);
        acco[1][dt] = __builtin_amdgcn_mfma_f32_16x16x32_bf16(vf, pf1.v, acco[1][dt], 0,0,0);
      }
      __builtin_amdgcn_s_setprio(0);
    }
  }

  // ---- epilogue: accl rows are all identical = l(q=lane&15); lane-local ----
  #pragma unroll
  for (int t=0;t<2;t++){
    float inv = 1.f / accl[t][0];
    u16* dst = Mg + (size_t)(b*2048 + q0 + t*16 + lr)*1024 + h*64;
    #pragma unroll
    for (int dt=0;dt<4;dt++){
      bf16x4 o2;
      #pragma unroll
      for (int rg=0;rg<4;rg++) o2[rg] = (short)f2bf(acco[t][dt][rg]*inv);
      *(bf16x4*)(dst + dt*16 + quad*4) = o2;
    }
  }
}

extern "C" void kernel_launch(void* const* d_in, const int* in_sizes, int n_in,
                              void* d_out, int out_size, void* d_ws, size_t ws_size,
                              hipStream_t stream){
  const float* q  = (const float*)d_in[0];
  const float* k  = (const float*)d_in[1];
  const float* v  = (const float*)d_in[2];
  const float* Wq = (const float*)d_in[3];
  const float* bq = (const float*)d_in[4];
  const float* Wk = (const float*)d_in[5];
  const float* bk = (const float*)d_in[6];
  const float* Wv = (const float*)d_in[7];
  const float* bv = (const float*)d_in[8];
  const float* Wo = (const float*)d_in[9];
  const float* bo = (const float*)d_in[10];
  const float* Wc = (const float*)d_in[11];
  const float* bc = (const float*)d_in[12];
  char* ws = (char*)d_ws;
  u16* qb  = (u16*)(ws + (size_t)0*MB);
  u16* kb  = (u16*)(ws + (size_t)8*MB);
  u16* vb  = (u16*)(ws + (size_t)16*MB);
  u16* Wqt = (u16*)(ws + (size_t)24*MB);
  u16* Wkt = (u16*)(ws + (size_t)26*MB);
  u16* Wvt = (u16*)(ws + (size_t)28*MB);
  u16* Wot = (u16*)(ws + (size_t)30*MB);
  u16* Wct = (u16*)(ws + (size_t)32*MB);
  u16* Qb  = (u16*)(ws + (size_t)34*MB);
  u16* Kr  = (u16*)(ws + (size_t)42*MB);
  u16* Vr  = (u16*)(ws + (size_t)50*MB);
  u16* Mg  = (u16*)(ws + (size_t)58*MB);

  dim3 blk(256,1,1);
  hipLaunchKernelGGL(conv_all, dim3(4096,1,4), blk, 0, stream,
                     q,k,v, qb,kb,vb, Wq,Wk,Wv,Wo,Wc, Wqt,Wkt,Wvt,Wot,Wct);
  hipLaunchKernelGGL(qkv_gemm, dim3(8,32,3),   blk, 0, stream, qb,kb,vb, Wqt,Wkt,Wvt, bq,bk,bv, Qb,Kr,Vr);
  hipLaunchKernelGGL(attn,     dim3(16,32,1),  blk, 0, stream, Qb, Kr, Vr, Mg);
  hipLaunchKernelGGL(out_gemm, dim3(8,32,2),   blk, 0, stream, Mg, Wct, Wot, bc, bo, (float*)d_out);
}

// Round 13
// 225.094 us; speedup vs baseline: 1.0865x; 1.0168x over previous
//
#include <hip/hip_runtime.h>
#include <stdint.h>

typedef unsigned short u16;
typedef short bf16x8 __attribute__((ext_vector_type(8)));
typedef short bf16x4 __attribute__((ext_vector_type(4)));
typedef float f32x4 __attribute__((ext_vector_type(4)));

#define MB (1u<<20)
#define CL2 0.18033688f   // log2(e)/sqrt(DK)

static __device__ __forceinline__ u16 f2bf(float x){
  union { float f; unsigned u; } v; v.f = x;
  return (u16)((v.u + 0x7FFFu + ((v.u >> 16) & 1u)) >> 16);
}

static __device__ __forceinline__ void gld_lds16(const void* g, void* l){
  __builtin_amdgcn_global_load_lds((const __attribute__((address_space(1))) unsigned int*)g,
                                   (__attribute__((address_space(3))) unsigned int*)l, 16, 0, 0);
}

// round-half-up f32 pair -> packed bf16x2 via v_perm (r4-verified; do NOT use
// v_cvt_pk_bf16_f32 here — r5 showed it breaks numerics on this toolchain).
static __device__ __forceinline__ int pack_bf16(float a, float b){
  unsigned ua = __float_as_uint(a) + 0x8000u;
  unsigned ub = __float_as_uint(b) + 0x8000u;
  return (int)__builtin_amdgcn_perm(ub, ua, 0x07060302u);
}

// ------------- fused prologue: qkv f32->bf16 + weight transpose, 1-D compact grid -------------
// r13: 8 elems/thread (32B read, 16B write) and no empty-slice dispatches
// (r12's z=4 grid wasted 2816 no-op blocks). blocks 0..6143: qkv convert
// (2048 per tensor); blocks 6144..7423: weight transpose (256 per weight).
__global__ void conv_all(const float* __restrict__ q, const float* __restrict__ k, const float* __restrict__ v,
                         u16* __restrict__ qb, u16* __restrict__ kb, u16* __restrict__ vb,
                         const float* W0,const float* W1,const float* W2,const float* W3,const float* W4,
                         u16* T0,u16* T1,u16* T2,u16* T3,u16* T4){
  __shared__ u16 t[64][65];
  const int bid = blockIdx.x;
  if (bid < 6144){
    const int ts = bid >> 11;              // tensor select
    const float* s = ts==0 ? q : (ts==1 ? k : v);
    u16* d = ts==0 ? qb : (ts==1 ? kb : vb);
    int i = ((bid & 2047)*256 + threadIdx.x)*8;
    float4 f0 = *(const float4*)(s + i);
    float4 f1 = *(const float4*)(s + i + 4);
    bf16x8 o;
    o[0]=(short)f2bf(f0.x); o[1]=(short)f2bf(f0.y); o[2]=(short)f2bf(f0.z); o[3]=(short)f2bf(f0.w);
    o[4]=(short)f2bf(f1.x); o[5]=(short)f2bf(f1.y); o[6]=(short)f2bf(f1.z); o[7]=(short)f2bf(f1.w);
    *(bf16x8*)(d + i) = o;
    return;
  }
  const int wid = bid - 6144;              // 5 weights x 256 tiles
  const int wsel = wid >> 8;
  const float* W = wsel==0?W0:wsel==1?W1:wsel==2?W2:wsel==3?W3:W4;
  u16* T = wsel==0?T0:wsel==1?T1:wsel==2?T2:wsel==3?T3:T4;
  const int idx2 = wid & 255;
  int k0 = (idx2 & 15)*64, n0 = (idx2 >> 4)*64;
  for (int i=0;i<16;i++){
    int idx = i*256 + threadIdx.x;
    int r = idx >> 6, c = idx & 63;
    t[r][c] = f2bf(W[(size_t)(k0+r)*1024 + n0 + c]);
  }
  __syncthreads();
  for (int i=0;i<2;i++){
    int idx = i*256 + threadIdx.x;
    int nl = idx >> 3, kc = idx & 7;
    bf16x8 o;
    #pragma unroll
    for (int j=0;j<8;j++) o[j] = (short)t[kc*8+j][nl];
    *(bf16x8*)(T + (size_t)(n0+nl)*1024 + k0 + kc*8) = o;
  }
}

// ---------------- 128x128 bf16 MFMA GEMM, B pre-transposed (Bt[n][k]) ----------------
// BK=64; LDS declared once at kernel scope and passed in (r3: per-instantiation
// __shared__ tripled LDS -> 1 block/CU). 3-bit XOR swizzle keeps ds_read_b128
// conflict-free. XCD-aware bijective block swizzle for L2 locality.
// MODE 0: bf16 row-major; 1: f32 row-major; 2: K attn layout; 3: V attn layout
// (x32-PV fragment order, see attn); 4: bf16 *CL2 (Q)
template<int MODE>
static __device__ __forceinline__ void gemm_bt_dev(u16* __restrict__ As, u16* __restrict__ Bs,
                                                   const u16* __restrict__ A, const u16* __restrict__ Bt,
                                                   const float* __restrict__ bias, void* __restrict__ Cout){
  const int tid = threadIdx.x, lane = tid & 63, w = tid >> 6;
  const int wm = w >> 1, wn = w & 1, quad = lane >> 4, lr = lane & 15;
  // bijective XCD swizzle over the 256 blocks of this z-slice (grid 8 x 32, nwg%8==0)
  const int fid = blockIdx.y * 8 + blockIdx.x;
  const int o   = (fid & 7) * 32 + (fid >> 3);
  const int n0  = (o & 7) * 128, m0 = (o >> 3) * 128;
  f32x4 acc[4][4] = {};
  const u16* Ab = A + (size_t)m0*1024;
  const u16* Bb = Bt + (size_t)n0*1024;
  // staging: 8 lanes per 128B row; issue j covers rows j*32 + w*8 .. +8
  const int srow_base = w*8 + (lane >> 3);
  const int sg = lane & 7;
  for (int k0 = 0; k0 < 1024; k0 += 64){
    #pragma unroll
    for (int j = 0; j < 4; ++j){
      int row = j*32 + srow_base;
      int g = sg ^ (row & 7);
      gld_lds16(Ab + (size_t)row*1024 + k0 + g*8, As + (j*32 + w*8)*64);
      gld_lds16(Bb + (size_t)row*1024 + k0 + g*8, Bs + (j*32 + w*8)*64);
    }
    __syncthreads();
    #pragma unroll
    for (int kk = 0; kk < 2; ++kk){
      bf16x8 af[4], bfr[4];
      #pragma unroll
      for (int i=0;i<4;i++){
        int ra = wm*64 + i*16 + lr;
        af[i]  = *(const bf16x8*)(As + ra*64 + (((kk*4+quad) ^ (ra & 7)))*8);
        int rb = wn*64 + i*16 + lr;
        bfr[i] = *(const bf16x8*)(Bs + rb*64 + (((kk*4+quad) ^ (rb & 7)))*8);
      }
      #pragma unroll
      for (int mi=0;mi<4;mi++)
        #pragma unroll
        for (int ni=0;ni<4;ni++)
          acc[mi][ni] = __builtin_amdgcn_mfma_f32_16x16x32_bf16(af[mi], bfr[ni], acc[mi][ni], 0, 0, 0);
    }
    __syncthreads();
  }
  #pragma unroll
  for (int mi=0;mi<4;mi++){
    int row = m0 + wm*64 + mi*16 + quad*4;
    #pragma unroll
    for (int ni=0;ni<4;ni++){
      int col = n0 + wn*64 + ni*16 + lr;
      float bb = bias[col];
      #pragma unroll
      for (int rg=0; rg<4; rg++){
        float vv = acc[mi][ni][rg] + bb;
        int r = row + rg;
        if (MODE == 0){
          ((u16*)Cout)[(size_t)r*1024 + col] = f2bf(vv);
        } else if (MODE == 4){
          ((u16*)Cout)[(size_t)r*1024 + col] = f2bf(vv * CL2);
        } else if (MODE == 1){
          ((float*)Cout)[(size_t)r*1024 + col] = vv;
        } else if (MODE == 2){
          // K: [bh][kb=16][hg=8][kvl=128][hl=8]
          int b2 = r >> 11, s = r & 2047, kb2 = s >> 7, kvl = s & 127;
          int hh = col >> 6, hg = (col & 63) >> 3, hl = col & 7;
          ((u16*)Cout)[((size_t)(b2*16+hh)*16 + kb2)*8192 + hg*1024 + kvl*8 + hl] = f2bf(vv);
        } else {
          // V for x32 PV: [bh][kb=16][mt2g=16][dd=64][j=8]
          // kv = 32*mt2 + 16*(j>>2) + 4*g + (j&3); elem = (mt2*4+g)*512 + dd*8 + j
          int b2 = r >> 11, s = r & 2047, kb2 = s >> 7, kvl = s & 127;
          int mt2v = kvl >> 5, gv = (kvl >> 2) & 3, jv = ((kvl >> 4) & 1)*4 + (kvl & 3);
          int hh = col >> 6, dd = col & 63;
          ((u16*)Cout)[((size_t)(b2*16+hh)*16 + kb2)*8192 + (size_t)(mt2v*4+gv)*512 + dd*8 + jv] = f2bf(vv);
        }
      }
    }
  }
}

__global__ void qkv_gemm(const u16* qb,const u16* kb,const u16* vb,
                         const u16* Wqt,const u16* Wkt,const u16* Wvt,
                         const float* bq,const float* bk,const float* bv,
                         u16* Qb,u16* Kr,u16* Vr){
  __shared__ u16 As[128*64];
  __shared__ u16 Bs[128*64];
  if (blockIdx.z == 0)      gemm_bt_dev<4>(As, Bs, qb, Wqt, bq, Qb);   // Q pre-scaled by CL2
  else if (blockIdx.z == 1) gemm_bt_dev<2>(As, Bs, kb, Wkt, bk, Kr);
  else                      gemm_bt_dev<3>(As, Bs, vb, Wvt, bv, Vr);
}

__global__ void out_gemm(const u16* Mg, const u16* Wct, const u16* Wot,
                         const float* bc, const float* bo, float* out){
  __shared__ u16 As[128*64];
  __shared__ u16 Bs[128*64];
  const u16* B = blockIdx.z==0? Wct : Wot;
  const float* bias = blockIdx.z==0? bc : bo;
  float* C = out + (blockIdx.z==0? 0 : 4194304);   // (c, h) concatenated
  gemm_bt_dev<1>(As, Bs, Mg, B, bias, C);
}

// ---------------- flash attention, transposed-score, no-max softmax ----------------
// r13 = r12 attn verbatim (best measured: 44.5 us; setprio A/B-confirmed +4%).
// Frozen: fusion/kv-split/QBLK256 all <=neutral (r5-r10); occupancy twice-refuted
// as the binding constraint; bank conflicts 0; barrier drain shown free (per-iter
// compute ~6700cyc >> HBM latency).
__global__ __launch_bounds__(256,2) void attn(const u16* __restrict__ Qb, const u16* __restrict__ Kr,
                                              const u16* __restrict__ Vr, u16* __restrict__ Mg){
  __shared__ u16 Ks[2][8192];
  __shared__ u16 Vs[2][8192];
  const int fid = blockIdx.y * 16 + blockIdx.x;        // nwg = 512, %8 == 0
  const int o   = (fid & 7) * 64 + (fid >> 3);
  const int qt = o & 15, bh = o >> 4, b = bh >> 4, h = bh & 15;
  const int tid = threadIdx.x, lane = tid & 63, w = tid >> 6;
  const int quad = lane >> 4, lr = lane & 15;
  const int q0 = qt*128 + w*32;

  bf16x8 aq[2][2];   // [q-subtile][ks]; Q pre-scaled by CL2
  #pragma unroll
  for (int t=0;t<2;t++)
    #pragma unroll
    for (int ks=0;ks<2;ks++)
      aq[t][ks] = *(const bf16x8*)(Qb + (size_t)(b*2048 + q0 + t*16 + lr)*1024 + h*64 + ks*32 + quad*8);

  f32x4 acco[2][4] = {};
  f32x4 accl[2] = {};
  const bf16x8 ones8 = {(short)0x3F80,(short)0x3F80,(short)0x3F80,(short)0x3F80,
                        (short)0x3F80,(short)0x3F80,(short)0x3F80,(short)0x3F80};

  const u16* Krb = Kr + (size_t)bh*131072;   // 16 kv-blocks * 8192 elems
  const u16* Vrb = Vr + (size_t)bh*131072;

  // prefetch kv-block 0 (4 chunks of 4 KB each per buffer)
  #pragma unroll
  for (int j=0;j<4;j++){
    gld_lds16(Krb + j*2048 + tid*8, &Ks[0][j*2048 + w*512]);
    gld_lds16(Vrb + j*2048 + tid*8, &Vs[0][j*2048 + w*512]);
  }

  for (int kb = 0; kb < 16; kb++){
    __syncthreads();                       // staged data for kb now visible
    const int cur = kb & 1;
    if (kb < 15){
      const u16* kg = Krb + (size_t)(kb+1)*8192;
      const u16* vg = Vrb + (size_t)(kb+1)*8192;
      #pragma unroll
      for (int j=0;j<4;j++){
        gld_lds16(kg + j*2048 + tid*8, &Ks[cur^1][j*2048 + w*512]);
        gld_lds16(vg + j*2048 + tid*8, &Vs[cur^1][j*2048 + w*512]);
      }
    }
    const u16* Ksc = Ks[cur];
    const u16* Vsc = Vs[cur];

    // ---- per 32-kv pair of subtiles: QK -> exp/pack -> l -> PV, all native x32 ----
    #pragma unroll
    for (int mt2=0;mt2<4;mt2++){
      f32x4 ae0 = {}, ae1 = {}, ao0 = {}, ao1 = {};
      __builtin_amdgcn_s_setprio(1);
      {
        bf16x8 kf0 = *(const bf16x8*)(Ksc + (0*4+quad)*1024 + ((2*mt2)*16+lr)*8);
        bf16x8 kf1 = *(const bf16x8*)(Ksc + (1*4+quad)*1024 + ((2*mt2)*16+lr)*8);
        ae0 = __builtin_amdgcn_mfma_f32_16x16x32_bf16(kf0, aq[0][0], ae0, 0,0,0);
        ae1 = __builtin_amdgcn_mfma_f32_16x16x32_bf16(kf0, aq[1][0], ae1, 0,0,0);
        ae0 = __builtin_amdgcn_mfma_f32_16x16x32_bf16(kf1, aq[0][1], ae0, 0,0,0);
        ae1 = __builtin_amdgcn_mfma_f32_16x16x32_bf16(kf1, aq[1][1], ae1, 0,0,0);
      }
      {
        bf16x8 kf0 = *(const bf16x8*)(Ksc + (0*4+quad)*1024 + ((2*mt2+1)*16+lr)*8);
        bf16x8 kf1 = *(const bf16x8*)(Ksc + (1*4+quad)*1024 + ((2*mt2+1)*16+lr)*8);
        ao0 = __builtin_amdgcn_mfma_f32_16x16x32_bf16(kf0, aq[0][0], ao0, 0,0,0);
        ao1 = __builtin_amdgcn_mfma_f32_16x16x32_bf16(kf0, aq[1][0], ao1, 0,0,0);
        ao0 = __builtin_amdgcn_mfma_f32_16x16x32_bf16(kf1, aq[0][1], ao0, 0,0,0);
        ao1 = __builtin_amdgcn_mfma_f32_16x16x32_bf16(kf1, aq[1][1], ao1, 0,0,0);
      }
      __builtin_amdgcn_s_setprio(0);

      // p = exp2(s'); pack even-mt into elems 0..3, odd-mt into 4..7 (x32 B-frag order)
      union { int4 i4; bf16x8 v; } pf0, pf1;
      pf0.i4.x = pack_bf16(__builtin_amdgcn_exp2f(ae0[0]), __builtin_amdgcn_exp2f(ae0[1]));
      pf0.i4.y = pack_bf16(__builtin_amdgcn_exp2f(ae0[2]), __builtin_amdgcn_exp2f(ae0[3]));
      pf0.i4.z = pack_bf16(__builtin_amdgcn_exp2f(ao0[0]), __builtin_amdgcn_exp2f(ao0[1]));
      pf0.i4.w = pack_bf16(__builtin_amdgcn_exp2f(ao0[2]), __builtin_amdgcn_exp2f(ao0[3]));
      pf1.i4.x = pack_bf16(__builtin_amdgcn_exp2f(ae1[0]), __builtin_amdgcn_exp2f(ae1[1]));
      pf1.i4.y = pack_bf16(__builtin_amdgcn_exp2f(ae1[2]), __builtin_amdgcn_exp2f(ae1[3]));
      pf1.i4.z = pack_bf16(__builtin_amdgcn_exp2f(ao1[0]), __builtin_amdgcn_exp2f(ao1[1]));
      pf1.i4.w = pack_bf16(__builtin_amdgcn_exp2f(ao1[2]), __builtin_amdgcn_exp2f(ao1[3]));

      __builtin_amdgcn_s_setprio(1);
      // l via native x32: every C row = sum over this 32-kv chunk
      accl[0] = __builtin_amdgcn_mfma_f32_16x16x32_bf16(ones8, pf0.v, accl[0], 0,0,0);
      accl[1] = __builtin_amdgcn_mfma_f32_16x16x32_bf16(ones8, pf1.v, accl[1], 0,0,0);

      // O^T += V^T * P^T (32 kv per op; vf read feeds both q-subtiles)
      #pragma unroll
      for (int dt=0;dt<4;dt++){
        bf16x8 vf = *(const bf16x8*)(Vsc + (mt2*4+quad)*512 + (dt*16+lr)*8);
        acco[0][dt] = __builtin_amdgcn_mfma_f32_16x16x32_bf16(vf, pf0.v, acco[0][dt], 0,0,0);
        acco[1][dt] = __builtin_amdgcn_mfma_f32_16x16x32_bf16(vf, pf1.v, acco[1][dt], 0,0,0);
      }
      __builtin_amdgcn_s_setprio(0);
    }
  }

  // ---- epilogue: accl rows are all identical = l(q=lane&15); lane-local ----
  #pragma unroll
  for (int t=0;t<2;t++){
    float inv = 1.f / accl[t][0];
    u16* dst = Mg + (size_t)(b*2048 + q0 + t*16 + lr)*1024 + h*64;
    #pragma unroll
    for (int dt=0;dt<4;dt++){
      bf16x4 o2;
      #pragma unroll
      for (int rg=0;rg<4;rg++) o2[rg] = (short)f2bf(acco[t][dt][rg]*inv);
      *(bf16x4*)(dst + dt*16 + quad*4) = o2;
    }
  }
}

extern "C" void kernel_launch(void* const* d_in, const int* in_sizes, int n_in,
                              void* d_out, int out_size, void* d_ws, size_t ws_size,
                              hipStream_t stream){
  const float* q  = (const float*)d_in[0];
  const float* k  = (const float*)d_in[1];
  const float* v  = (const float*)d_in[2];
  const float* Wq = (const float*)d_in[3];
  const float* bq = (const float*)d_in[4];
  const float* Wk = (const float*)d_in[5];
  const float* bk = (const float*)d_in[6];
  const float* Wv = (const float*)d_in[7];
  const float* bv = (const float*)d_in[8];
  const float* Wo = (const float*)d_in[9];
  const float* bo = (const float*)d_in[10];
  const float* Wc = (const float*)d_in[11];
  const float* bc = (const float*)d_in[12];
  char* ws = (char*)d_ws;
  u16* qb  = (u16*)(ws + (size_t)0*MB);
  u16* kb  = (u16*)(ws + (size_t)8*MB);
  u16* vb  = (u16*)(ws + (size_t)16*MB);
  u16* Wqt = (u16*)(ws + (size_t)24*MB);
  u16* Wkt = (u16*)(ws + (size_t)26*MB);
  u16* Wvt = (u16*)(ws + (size_t)28*MB);
  u16* Wot = (u16*)(ws + (size_t)30*MB);
  u16* Wct = (u16*)(ws + (size_t)32*MB);
  u16* Qb  = (u16*)(ws + (size_t)34*MB);
  u16* Kr  = (u16*)(ws + (size_t)42*MB);
  u16* Vr  = (u16*)(ws + (size_t)50*MB);
  u16* Mg  = (u16*)(ws + (size_t)58*MB);

  dim3 blk(256,1,1);
  hipLaunchKernelGGL(conv_all, dim3(7424,1,1), blk, 0, stream,
                     q,k,v, qb,kb,vb, Wq,Wk,Wv,Wo,Wc, Wqt,Wkt,Wvt,Wot,Wct);
  hipLaunchKernelGGL(qkv_gemm, dim3(8,32,3),   blk, 0, stream, qb,kb,vb, Wqt,Wkt,Wvt, bq,bk,bv, Qb,Kr,Vr);
  hipLaunchKernelGGL(attn,     dim3(16,32,1),  blk, 0, stream, Qb, Kr, Vr, Mg);
  hipLaunchKernelGGL(out_gemm, dim3(8,32,2),   blk, 0, stream, Mg, Wct, Wot, bc, bo, (float*)d_out);
}